// Round 1
// baseline (160.821 us; speedup 1.0000x reference)
//
#include <hip/hip_runtime.h>
#include <stdint.h>

#define TDIM 512
#define NDIM 256
#define BDIM 128
#define CGAP 5
#define DELTA_C 0.05f
#define TC 64                    // chunk rows
#define NCHUNK (TDIM / TC)       // 8

// Async 16B global->LDS. LDS dest = wave-uniform base + lane*16.
__device__ __forceinline__ void gld16(const float* g, float* l) {
  __builtin_amdgcn_global_load_lds(
      (const __attribute__((address_space(1))) void*)g,
      (__attribute__((address_space(3))) void*)l,
      16, 0, 0);
}

// Load 64 rows x 64 floats (one chunk) as 16 calls of 4 rows each.
// Lane i of call rg fetches row (rg*4 + i/16), cols (i%16)*4..+3 -> LDS
// row-major [64][64] at lbase (lane i lands at lbase + i*16 bytes).
__device__ __forceinline__ void issue_chunk(const float* gbase, float* lbase,
                                            int lane_off) {
#pragma unroll
  for (int rg = 0; rg < 16; ++rg) {
    gld16(gbase + rg * 4 * NDIM + lane_off, lbase + rg * 256);
  }
}

extern "C" __global__ void __launch_bounds__(64)
stca_kernel(const float* __restrict__ vmem, const int* __restrict__ labels,
            const float* __restrict__ ratio_p, float* __restrict__ out) {
  __shared__ float tile[2][TC * 64];
  const int lane = threadIdx.x;            // neuron within slice
  const int blk  = blockIdx.x;             // 512 blocks: (b, n-quarter)
  const int b    = blk >> 2;
  const int n0   = (blk & 3) << 6;
  const int n    = n0 + lane;

  const float ratio = ratio_p[0];
  const int   label = labels[b * NDIM + n];
  const float* gbase = vmem + (size_t)b * TDIM * NDIM + n0;
  // lane i covers row i/16, 4 floats at col (i%15..)*4 within the 64-wide slice
  const int lane_off = ((lane >> 4) * NDIM) + ((lane & 15) << 2);

  issue_chunk(gbase, &tile[0][0], lane_off);   // prefetch chunk 0

  // streaming scan state
  int   last_spike = -1000;
  int   nclu = 0, cur_count = 0, best_count = 0x7fffffff;
  float cur_max = -INFINITY;      // max v over [cur_first .. t]
  float cur_maxlast = -INFINITY;  // max v over [cur_first .. last spike]
  float best_max = -INFINITY;     // span-max of best (min-count, first-tie) cluster
  float umax = -INFINITY;         // max v over unmasked positions
  int   has_un = 0;
  unsigned hist = 0u;             // spike bits for times [t-10 .. t]
  float vd0 = 0.f, vd1 = 0.f, vd2 = 0.f, vd3 = 0.f, vd4 = 0.f, vd5 = 0.f;

  for (int c = 0; c < NCHUNK; ++c) {
    if (c + 1 < NCHUNK) {
      issue_chunk(gbase + (size_t)(c + 1) * TC * NDIM, &tile[(c + 1) & 1][0],
                  lane_off);
      // chunk c's 16 loads are >=16 ops older than the tail -> complete
      asm volatile("s_waitcnt vmcnt(16)" ::: "memory");
    } else {
      asm volatile("s_waitcnt vmcnt(0)" ::: "memory");
    }
    const float* tl = &tile[c & 1][0];
    const int t0 = c * TC;
#pragma unroll 16
    for (int r = 0; r < TC; ++r) {
      const int t = t0 + r;
      const float v = tl[(r << 6) + lane];
      // delay line: vd_k = v[t-k] after this shift
      vd5 = vd4; vd4 = vd3; vd3 = vd2; vd2 = vd1; vd1 = vd0; vd0 = v;

      const bool spike = v >= 0.0f;
      const bool isstart = spike && ((t - last_spike) > CGAP);
      // close previous cluster (strict < keeps first minimal = argmin ties)
      const bool better = isstart && (nclu > 0) && (cur_count < best_count);
      best_count = better ? cur_count : best_count;
      best_max   = better ? cur_maxlast : best_max;
      nclu += isstart ? 1 : 0;
      cur_max = isstart ? v : fmaxf(cur_max, v);
      cur_maxlast = spike ? cur_max : cur_maxlast;  // snapshot at spikes only
      cur_count = isstart ? 0 : cur_count;
      cur_count += spike ? 1 : 0;
      last_spike = spike ? t : last_spike;

      // unmask decision for p = t - C: window [p-5, p+5] == hist's 11 bits
      hist = ((hist << 1) | (spike ? 1u : 0u)) & 0x7FFu;
      const bool un = (hist == 0u) && (t >= CGAP);
      umax = un ? fmaxf(umax, vd5) : umax;
      has_un |= un ? 1 : 0;
    }
  }

  // epilogue: decide positions p = T-6+j for j=1..5
#pragma unroll
  for (int j = 1; j <= CGAP; ++j) {
    hist = (hist << 1) & 0x7FFu;
    vd5 = vd4; vd4 = vd3; vd3 = vd2; vd2 = vd1; vd1 = vd0; vd0 = -INFINITY;
    const bool un = (hist == 0u);
    umax = un ? fmaxf(umax, vd5) : umax;
    has_un |= un ? 1 : 0;
  }
  // close final cluster
  if (nclu > 0 && cur_count < best_count) best_max = cur_maxlast;

  const float ncf    = (float)nclu;
  const float margin = DELTA_C * ratio * ncf;
  // has_un==0 (full dilation coverage) is probabilistically impossible at
  // p(spike)=6.7%, T=512; reference would use a threefry-random spike there.
  const float under_term = has_un ? (-umax) : 0.0f;
  const float under = (label > nclu) ? (under_term + margin) : 0.0f;
  const float over  = (label < nclu) ? (best_max + margin) : 0.0f;

  out[1 + b * NDIM + n] = ncf;   // spike_output

  float sum = under + over;
#pragma unroll
  for (int off = 32; off > 0; off >>= 1) sum += __shfl_down(sum, off);
  if (lane == 0) atomicAdd(out, sum);    // loss
}

extern "C" void kernel_launch(void* const* d_in, const int* in_sizes, int n_in,
                              void* d_out, int out_size, void* d_ws,
                              size_t ws_size, hipStream_t stream) {
  const float* vmem   = (const float*)d_in[0];
  // d_in[1] (vlastmem) is unused by the loss math -> never read (saves 64 MiB)
  const int*   labels = (const int*)d_in[2];
  const float* ratio  = (const float*)d_in[3];
  float* out = (float*)d_out;

  hipMemsetAsync(d_out, 0, sizeof(float), stream);  // zero the loss accumulator
  dim3 grid(BDIM * (NDIM / 64));   // 512 single-wave blocks
  dim3 block(64);
  hipLaunchKernelGGL(stca_kernel, grid, block, 0, stream, vmem, labels, ratio,
                     out);
}